// Round 10
// baseline (110.246 us; speedup 1.0000x reference)
//
#include <hip/hip_runtime.h>

#define THRESH 1.0f

typedef float fvec4 __attribute__((ext_vector_type(4)));

__device__ __forceinline__ float rl(float v, int l) {
    return __int_as_float(__builtin_amdgcn_readlane(__float_as_int(v), l));
}

// ---------- W transpose: Wt[k][m] = W[m][k] (into d_ws) ----------
__global__ __launch_bounds__(256) void transpose_kernel(
    const float* __restrict__ W, float* __restrict__ Wt, int M, int D)
{
    __shared__ float tile[32][33];
    const int tilesK = D / 32;
    const int bx = blockIdx.x % tilesK;   // k tile
    const int by = blockIdx.x / tilesK;   // m tile
    const int lx = threadIdx.x & 31;
    const int ly = threadIdx.x >> 5;      // 0..7
    #pragma unroll
    for (int j = 0; j < 4; ++j)
        tile[ly + j * 8][lx] = W[(size_t)(by * 32 + ly + j * 8) * D + bx * 32 + lx];
    __syncthreads();
    #pragma unroll
    for (int j = 0; j < 4; ++j)
        Wt[(size_t)(bx * 32 + ly + j * 8) * M + by * 32 + lx] = tile[lx][ly + j * 8];
}

// ---------- row-pair kernel, 512 threads, asymmetric wave roles ----------
// Wave 0: wave-local softmax for row b0 (lane owns logits 4*lane..4*lane+3;
//         Wt4 coalesced from L2, x broadcast via readlane, shuffle-only
//         reductions — NO barrier). Wave 1: same for row b1.
// Waves 2-7: start the HBM neuron stream immediately.
// Uneven m-split {46,70,70,70} compensates the prologue waves' late start.
// One __syncthreads at the end for the count combine. 2 blocks/CU = 16 w/CU.
__global__ __launch_bounds__(512, 4) void rowpair512b_kernel(
    const float* __restrict__ x, const float* __restrict__ mem,
    const float* __restrict__ Wt, const float* __restrict__ bias,
    float* __restrict__ mem_new, float* __restrict__ scores,
    float* __restrict__ mixed, int plane4)
{
    const int b0   = blockIdx.x * 2;
    const int tid  = threadIdx.x;
    const int wave = tid >> 6;
    const int lane = tid & 63;
    const int q    = tid >> 7;            // stream m-segment 0..3
    const int pp   = tid & 127;           // position in 2-row panel
    const int pos4 = b0 * 64 + pp;        // fvec4 index in [B,D] plane

    __shared__ fvec4 sc_lds[2][64];       // scores per row (fvec4 per lane)
    __shared__ fvec4 cnt_lds[4][128];

    const fvec4* mem4 = reinterpret_cast<const fvec4*>(mem);
    fvec4* out4       = reinterpret_cast<fvec4*>(mem_new);
    const fvec4* x4   = reinterpret_cast<const fvec4*>(x);

    if (wave < 2) {
        // ---- barrier-free prologue: softmax of row (b0+wave) ----
        const int row = b0 + wave;
        const fvec4* Wt4 = reinterpret_cast<const fvec4*>(Wt);
        const fvec4 xq = x4[(size_t)row * 64 + lane];
        fvec4 acc = {0.f, 0.f, 0.f, 0.f};
        #pragma unroll 4
        for (int j = 0; j < 64; ++j) {
            const float xk0 = rl(xq.x, j);
            const float xk1 = rl(xq.y, j);
            const float xk2 = rl(xq.z, j);
            const float xk3 = rl(xq.w, j);
            const fvec4 w0 = Wt4[(size_t)(4 * j + 0) * 64 + lane];
            const fvec4 w1 = Wt4[(size_t)(4 * j + 1) * 64 + lane];
            const fvec4 w2 = Wt4[(size_t)(4 * j + 2) * 64 + lane];
            const fvec4 w3 = Wt4[(size_t)(4 * j + 3) * 64 + lane];
            acc.x = fmaf(w0.x, xk0, acc.x);
            acc.y = fmaf(w0.y, xk0, acc.y);
            acc.z = fmaf(w0.z, xk0, acc.z);
            acc.w = fmaf(w0.w, xk0, acc.w);
            acc.x = fmaf(w1.x, xk1, acc.x);
            acc.y = fmaf(w1.y, xk1, acc.y);
            acc.z = fmaf(w1.z, xk1, acc.z);
            acc.w = fmaf(w1.w, xk1, acc.w);
            acc.x = fmaf(w2.x, xk2, acc.x);
            acc.y = fmaf(w2.y, xk2, acc.y);
            acc.z = fmaf(w2.z, xk2, acc.z);
            acc.w = fmaf(w2.w, xk2, acc.w);
            acc.x = fmaf(w3.x, xk3, acc.x);
            acc.y = fmaf(w3.y, xk3, acc.y);
            acc.z = fmaf(w3.z, xk3, acc.z);
            acc.w = fmaf(w3.w, xk3, acc.w);
        }
        const fvec4 bv = reinterpret_cast<const fvec4*>(bias)[lane];
        fvec4 lg;
        lg.x = acc.x + bv.x; lg.y = acc.y + bv.y;
        lg.z = acc.z + bv.z; lg.w = acc.w + bv.w;

        float mx = fmaxf(fmaxf(lg.x, lg.y), fmaxf(lg.z, lg.w));
        #pragma unroll
        for (int off = 32; off; off >>= 1) mx = fmaxf(mx, __shfl_xor(mx, off, 64));

        fvec4 e;
        e.x = expf(lg.x - mx); e.y = expf(lg.y - mx);
        e.z = expf(lg.z - mx); e.w = expf(lg.w - mx);
        float s = (e.x + e.y) + (e.z + e.w);
        #pragma unroll
        for (int off = 32; off; off >>= 1) s += __shfl_xor(s, off, 64);

        fvec4 sc;
        sc.x = e.x / s; sc.y = e.y / s; sc.z = e.z / s; sc.w = e.w / s;
        sc_lds[wave][lane] = sc;
        reinterpret_cast<fvec4*>(scores)[(size_t)row * 64 + lane] = sc;
    }

    // ---- neuron stream: m in [MB[q], MB[q+1]), bit-exact math ----
    const int MB[5] = {0, 46, 116, 186, 256};
    const int m0 = MB[q], m1 = MB[q + 1];

    const fvec4 xv = x4[pos4];            // L1/L2 hot
    float cx = 0.f, cy = 0.f, cz = 0.f, cw = 0.f;

    #pragma unroll 4
    for (int m = m0; m < m1; ++m) {
        const float bm = (float)m;
        const size_t off = (size_t)m * plane4 + pos4;
        const fvec4 mv = __builtin_nontemporal_load(&mem4[off]);
        fvec4 nv;
        nv.x = __fsub_rn(__fadd_rn(__fmul_rn(bm, mv.x), xv.x),
                         (mv.x - THRESH > 0.f) ? THRESH : 0.f);
        nv.y = __fsub_rn(__fadd_rn(__fmul_rn(bm, mv.y), xv.y),
                         (mv.y - THRESH > 0.f) ? THRESH : 0.f);
        nv.z = __fsub_rn(__fadd_rn(__fmul_rn(bm, mv.z), xv.z),
                         (mv.z - THRESH > 0.f) ? THRESH : 0.f);
        nv.w = __fsub_rn(__fadd_rn(__fmul_rn(bm, mv.w), xv.w),
                         (mv.w - THRESH > 0.f) ? THRESH : 0.f);
        __builtin_nontemporal_store(nv, &out4[off]);
        cx += (nv.x - THRESH > 0.f) ? 1.f : 0.f;
        cy += (nv.y - THRESH > 0.f) ? 1.f : 0.f;
        cz += (nv.z - THRESH > 0.f) ? 1.f : 0.f;
        cw += (nv.w - THRESH > 0.f) ? 1.f : 0.f;
    }

    fvec4 cv; cv.x = cx; cv.y = cy; cv.z = cz; cv.w = cw;
    cnt_lds[q][pp] = cv;
    __syncthreads();

    // ---- epilogue (waves 0-1): mixed = scores_flat * total spike count ----
    if (q == 0) {
        const fvec4 c0 = cnt_lds[0][pp];
        const fvec4 c1 = cnt_lds[1][pp];
        const fvec4 c2 = cnt_lds[2][pp];
        const fvec4 c3 = cnt_lds[3][pp];
        fvec4 c;
        c.x = (c0.x + c1.x) + (c2.x + c3.x);
        c.y = (c0.y + c1.y) + (c2.y + c3.y);
        c.z = (c0.z + c1.z) + (c2.z + c3.z);
        c.w = (c0.w + c1.w) + (c2.w + c3.w);
        const fvec4 sc = sc_lds[pp >> 6][pp & 63];
        fvec4 r;
        r.x = sc.x * c.x; r.y = sc.y * c.y;
        r.z = sc.z * c.z; r.w = sc.w * c.w;
        reinterpret_cast<fvec4*>(mixed)[pos4] = r;
    }
}

// ---------- fallback kernels (used if ws too small / odd shapes) ----------
__global__ __launch_bounds__(256) void scores_kernel_fb(
    const float* __restrict__ x, const float* __restrict__ W,
    const float* __restrict__ bias, float* __restrict__ scores,
    int D, int M)
{
    const int b = blockIdx.x;
    __shared__ __align__(16) float x_lds[256];
    __shared__ float logits[256];
    __shared__ float wred[4];
    const int tid  = threadIdx.x;
    const int wave = tid >> 6;
    const int lane = tid & 63;
    x_lds[tid] = x[(size_t)b * D + tid];
    __syncthreads();
    const float4* W4 = reinterpret_cast<const float4*>(W);
    const float4  xv = reinterpret_cast<const float4*>(x_lds)[lane];
    for (int i = 0; i < 64; ++i) {
        const int m = wave * 64 + i;
        const float4 wv = W4[(size_t)m * 64 + lane];
        float pp = wv.x * xv.x + wv.y * xv.y + wv.z * xv.z + wv.w * xv.w;
        #pragma unroll
        for (int off = 32; off; off >>= 1) pp += __shfl_xor(pp, off, 64);
        if (lane == 0) logits[m] = pp + bias[m];
    }
    __syncthreads();
    float l = logits[tid];
    float mx = l;
    #pragma unroll
    for (int off = 32; off; off >>= 1) mx = fmaxf(mx, __shfl_xor(mx, off, 64));
    if (lane == 0) wred[wave] = mx;
    __syncthreads();
    mx = fmaxf(fmaxf(wred[0], wred[1]), fmaxf(wred[2], wred[3]));
    __syncthreads();
    const float e = expf(l - mx);
    float s = e;
    #pragma unroll
    for (int off = 32; off; off >>= 1) s += __shfl_xor(s, off, 64);
    if (lane == 0) wred[wave] = s;
    __syncthreads();
    const float tot = wred[0] + wred[1] + wred[2] + wred[3];
    scores[(size_t)b * M + tid] = e / tot;
}

__global__ __launch_bounds__(256) void neuron_kernel_fb(
    const float* __restrict__ x, const float* __restrict__ mem,
    const float* __restrict__ scores, float* __restrict__ mixed,
    float* __restrict__ mem_new, int M, int plane4)
{
    const int idx = blockIdx.x * 256 + threadIdx.x;
    if (idx >= plane4) return;
    const float4* x4   = reinterpret_cast<const float4*>(x);
    const float4* mem4 = reinterpret_cast<const float4*>(mem);
    const float4* sc4  = reinterpret_cast<const float4*>(scores);
    float4* out4       = reinterpret_cast<float4*>(mem_new);
    float4* mix4       = reinterpret_cast<float4*>(mixed);
    const float4 xv = x4[idx];
    float cx = 0.f, cy = 0.f, cz = 0.f, cw = 0.f;
    #pragma unroll 4
    for (int m = 0; m < M; ++m) {
        const float bm = (float)m;
        const size_t off = (size_t)m * plane4 + idx;
        const float4 mv = mem4[off];
        float4 nv;
        nv.x = __fsub_rn(__fadd_rn(__fmul_rn(bm, mv.x), xv.x),
                         (mv.x - THRESH > 0.f) ? THRESH : 0.f);
        nv.y = __fsub_rn(__fadd_rn(__fmul_rn(bm, mv.y), xv.y),
                         (mv.y - THRESH > 0.f) ? THRESH : 0.f);
        nv.z = __fsub_rn(__fadd_rn(__fmul_rn(bm, mv.z), xv.z),
                         (mv.z - THRESH > 0.f) ? THRESH : 0.f);
        nv.w = __fsub_rn(__fadd_rn(__fmul_rn(bm, mv.w), xv.w),
                         (mv.w - THRESH > 0.f) ? THRESH : 0.f);
        out4[off] = nv;
        cx += (nv.x - THRESH > 0.f) ? 1.f : 0.f;
        cy += (nv.y - THRESH > 0.f) ? 1.f : 0.f;
        cz += (nv.z - THRESH > 0.f) ? 1.f : 0.f;
        cw += (nv.w - THRESH > 0.f) ? 1.f : 0.f;
    }
    const float4 sc = sc4[idx];
    float4 mx;
    mx.x = sc.x * cx; mx.y = sc.y * cy; mx.z = sc.z * cz; mx.w = sc.w * cw;
    mix4[idx] = mx;
}

extern "C" void kernel_launch(void* const* d_in, const int* in_sizes, int n_in,
                              void* d_out, int out_size, void* d_ws, size_t ws_size,
                              hipStream_t stream) {
    const float* x    = (const float*)d_in[0];
    const float* mem  = (const float*)d_in[1];
    const float* W    = (const float*)d_in[2];
    const float* bias = (const float*)d_in[3];

    const int M = in_sizes[3];             // 256
    const int D = in_sizes[2] / M;         // 256
    const int B = in_sizes[0] / D;         // 1024
    const int plane  = B * D;              // 262144
    const int plane4 = plane / 4;          // 65536

    float* out_mixed  = (float*)d_out;                       // [B*D]
    float* out_mem    = out_mixed + plane;                   // [M*B*D]
    float* out_scores = out_mem + (size_t)M * plane;         // [B*M]

    const size_t wt_bytes = (size_t)M * D * sizeof(float);   // 256 KB

    const bool shapes_ok = (D == 256) && (M == 256) && (B % 2 == 0);

    if (shapes_ok && ws_size >= wt_bytes) {
        float* Wt = (float*)d_ws;
        transpose_kernel<<<(M / 32) * (D / 32), 256, 0, stream>>>(W, Wt, M, D);
        rowpair512b_kernel<<<B / 2, 512, 0, stream>>>(
            x, mem, Wt, bias, out_mem, out_scores, out_mixed, plane4);
    } else {
        scores_kernel_fb<<<B, 256, 0, stream>>>(x, W, bias, out_scores, D, M);
        neuron_kernel_fb<<<(plane4 + 255) / 256, 256, 0, stream>>>(
            x, mem, out_scores, out_mixed, out_mem, M, plane4);
    }
}

// Round 11
// 109.329 us; speedup vs baseline: 1.0084x; 1.0084x over previous
//
#include <hip/hip_runtime.h>

#define THRESH 1.0f

typedef float fvec4 __attribute__((ext_vector_type(4)));

__device__ __forceinline__ float rl(float v, int l) {
    return __int_as_float(__builtin_amdgcn_readlane(__float_as_int(v), l));
}

// ---------- W transpose: Wt[k][m] = W[m][k] (into d_ws) ----------
__global__ __launch_bounds__(256) void transpose_kernel(
    const float* __restrict__ W, float* __restrict__ Wt, int M, int D)
{
    __shared__ float tile[32][33];
    const int tilesK = D / 32;
    const int bx = blockIdx.x % tilesK;   // k tile
    const int by = blockIdx.x / tilesK;   // m tile
    const int lx = threadIdx.x & 31;
    const int ly = threadIdx.x >> 5;      // 0..7
    #pragma unroll
    for (int j = 0; j < 4; ++j)
        tile[ly + j * 8][lx] = W[(size_t)(by * 32 + ly + j * 8) * D + bx * 32 + lx];
    __syncthreads();
    #pragma unroll
    for (int j = 0; j < 4; ++j)
        Wt[(size_t)(bx * 32 + ly + j * 8) * M + by * 32 + lx] = tile[lx][ly + j * 8];
}

// ---------- row-pair kernel v2: block = rows (b0, b0+1), 256 threads ----------
// Prologue: IDENTICAL to R7 (thread tid owns logit m=tid for both rows).
// Stream: wave q owns m-quarter [64q, 64q+64); lane l owns positions l and
//   l+64 of the 2-row panel -> each wave covers the full 2KB panel per m-step
//   (2 adjacent 1KB requests), 16 loads in flight per thread via unroll 8.
// Epilogue: threads 0..127 combine 4 quarter-counts (exact ints) and write
//   mixed = scores * count.
__global__ __launch_bounds__(256) void rowpair_kernel(
    const float* __restrict__ x, const float* __restrict__ mem,
    const float* __restrict__ Wt, const float* __restrict__ bias,
    float* __restrict__ mem_new, float* __restrict__ scores,
    float* __restrict__ mixed, int plane4)
{
    const int b0   = blockIdx.x * 2;
    const int tid  = threadIdx.x;
    const int wave = tid >> 6;
    const int lane = tid & 63;

    __shared__ __align__(16) float sc_lds[2][256];
    __shared__ fvec4 cnt_lds[4][128];
    __shared__ float wredm[2][4];
    __shared__ float wreds[2][4];

    const fvec4* x4c  = reinterpret_cast<const fvec4*>(x);
    const fvec4* mem4 = reinterpret_cast<const fvec4*>(mem);
    fvec4* out4       = reinterpret_cast<fvec4*>(mem_new);

    // ---- prologue (R7-exact): logits for both rows ----
    const fvec4 xq0 = x4c[(size_t)b0 * 64 + lane];
    const fvec4 xq1 = x4c[(size_t)(b0 + 1) * 64 + lane];

    float a0 = 0.f, a1 = 0.f;
    #pragma unroll 4
    for (int j = 0; j < 64; ++j) {
        const float w0 = Wt[(size_t)(4 * j + 0) * 256 + tid];
        const float w1 = Wt[(size_t)(4 * j + 1) * 256 + tid];
        const float w2 = Wt[(size_t)(4 * j + 2) * 256 + tid];
        const float w3 = Wt[(size_t)(4 * j + 3) * 256 + tid];
        a0 = fmaf(w0, rl(xq0.x, j), a0);
        a0 = fmaf(w1, rl(xq0.y, j), a0);
        a0 = fmaf(w2, rl(xq0.z, j), a0);
        a0 = fmaf(w3, rl(xq0.w, j), a0);
        a1 = fmaf(w0, rl(xq1.x, j), a1);
        a1 = fmaf(w1, rl(xq1.y, j), a1);
        a1 = fmaf(w2, rl(xq1.z, j), a1);
        a1 = fmaf(w3, rl(xq1.w, j), a1);
    }
    const float bv = bias[tid];
    const float l0 = a0 + bv, l1 = a1 + bv;

    float m0 = l0, m1 = l1;
    #pragma unroll
    for (int off = 32; off; off >>= 1) {
        m0 = fmaxf(m0, __shfl_xor(m0, off, 64));
        m1 = fmaxf(m1, __shfl_xor(m1, off, 64));
    }
    if (lane == 0) { wredm[0][wave] = m0; wredm[1][wave] = m1; }
    __syncthreads();
    m0 = fmaxf(fmaxf(wredm[0][0], wredm[0][1]), fmaxf(wredm[0][2], wredm[0][3]));
    m1 = fmaxf(fmaxf(wredm[1][0], wredm[1][1]), fmaxf(wredm[1][2], wredm[1][3]));

    const float e0 = expf(l0 - m0), e1 = expf(l1 - m1);
    float s0 = e0, s1 = e1;
    #pragma unroll
    for (int off = 32; off; off >>= 1) {
        s0 += __shfl_xor(s0, off, 64);
        s1 += __shfl_xor(s1, off, 64);
    }
    if (lane == 0) { wreds[0][wave] = s0; wreds[1][wave] = s1; }
    __syncthreads();
    const float t0 = wreds[0][0] + wreds[0][1] + wreds[0][2] + wreds[0][3];
    const float t1 = wreds[1][0] + wreds[1][1] + wreds[1][2] + wreds[1][3];

    const float sc0 = e0 / t0, sc1 = e1 / t1;
    sc_lds[0][tid] = sc0;
    sc_lds[1][tid] = sc1;
    scores[(size_t)b0 * 256 + tid]       = sc0;
    scores[(size_t)(b0 + 1) * 256 + tid] = sc1;

    // ---- stream: wave q = m-quarter; lane owns panel positions l, l+64 ----
    const int q     = wave;
    const int posA  = b0 * 64 + lane;       // fvec4 index in [B,D] plane
    const int posB  = posA + 64;
    const fvec4 xvA = x4c[posA];             // L2 hot
    const fvec4 xvB = x4c[posB];

    float cAx = 0.f, cAy = 0.f, cAz = 0.f, cAw = 0.f;
    float cBx = 0.f, cBy = 0.f, cBz = 0.f, cBw = 0.f;
    const int mstart = q * 64;

    #pragma unroll 8
    for (int mm = 0; mm < 64; ++mm) {
        const int m = mstart + mm;
        const float bm = (float)m;
        const size_t offA = (size_t)m * plane4 + posA;
        const size_t offB = offA + 64;
        const fvec4 mvA = __builtin_nontemporal_load(&mem4[offA]);
        const fvec4 mvB = __builtin_nontemporal_load(&mem4[offB]);

        fvec4 nvA, nvB;
        nvA.x = __fsub_rn(__fadd_rn(__fmul_rn(bm, mvA.x), xvA.x),
                          (mvA.x - THRESH > 0.f) ? THRESH : 0.f);
        nvA.y = __fsub_rn(__fadd_rn(__fmul_rn(bm, mvA.y), xvA.y),
                          (mvA.y - THRESH > 0.f) ? THRESH : 0.f);
        nvA.z = __fsub_rn(__fadd_rn(__fmul_rn(bm, mvA.z), xvA.z),
                          (mvA.z - THRESH > 0.f) ? THRESH : 0.f);
        nvA.w = __fsub_rn(__fadd_rn(__fmul_rn(bm, mvA.w), xvA.w),
                          (mvA.w - THRESH > 0.f) ? THRESH : 0.f);
        nvB.x = __fsub_rn(__fadd_rn(__fmul_rn(bm, mvB.x), xvB.x),
                          (mvB.x - THRESH > 0.f) ? THRESH : 0.f);
        nvB.y = __fsub_rn(__fadd_rn(__fmul_rn(bm, mvB.y), xvB.y),
                          (mvB.y - THRESH > 0.f) ? THRESH : 0.f);
        nvB.z = __fsub_rn(__fadd_rn(__fmul_rn(bm, mvB.z), xvB.z),
                          (mvB.z - THRESH > 0.f) ? THRESH : 0.f);
        nvB.w = __fsub_rn(__fadd_rn(__fmul_rn(bm, mvB.w), xvB.w),
                          (mvB.w - THRESH > 0.f) ? THRESH : 0.f);

        __builtin_nontemporal_store(nvA, &out4[offA]);
        __builtin_nontemporal_store(nvB, &out4[offB]);

        cAx += (nvA.x - THRESH > 0.f) ? 1.f : 0.f;
        cAy += (nvA.y - THRESH > 0.f) ? 1.f : 0.f;
        cAz += (nvA.z - THRESH > 0.f) ? 1.f : 0.f;
        cAw += (nvA.w - THRESH > 0.f) ? 1.f : 0.f;
        cBx += (nvB.x - THRESH > 0.f) ? 1.f : 0.f;
        cBy += (nvB.y - THRESH > 0.f) ? 1.f : 0.f;
        cBz += (nvB.z - THRESH > 0.f) ? 1.f : 0.f;
        cBw += (nvB.w - THRESH > 0.f) ? 1.f : 0.f;
    }
    fvec4 cvA; cvA.x = cAx; cvA.y = cAy; cvA.z = cAz; cvA.w = cAw;
    fvec4 cvB; cvB.x = cBx; cvB.y = cBy; cvB.z = cBz; cvB.w = cBw;
    cnt_lds[q][lane]      = cvA;
    cnt_lds[q][lane + 64] = cvB;
    __syncthreads();

    // ---- epilogue: mixed[pos] = scores_flat[pos] * total spike count ----
    if (tid < 128) {
        const int pp = tid;
        const fvec4 c0 = cnt_lds[0][pp];
        const fvec4 c1 = cnt_lds[1][pp];
        const fvec4 c2 = cnt_lds[2][pp];
        const fvec4 c3 = cnt_lds[3][pp];
        fvec4 c;
        c.x = (c0.x + c1.x) + (c2.x + c3.x);
        c.y = (c0.y + c1.y) + (c2.y + c3.y);
        c.z = (c0.z + c1.z) + (c2.z + c3.z);
        c.w = (c0.w + c1.w) + (c2.w + c3.w);
        const fvec4 sc = reinterpret_cast<const fvec4*>(sc_lds[pp >> 6])[pp & 63];
        fvec4 r;
        r.x = sc.x * c.x; r.y = sc.y * c.y;
        r.z = sc.z * c.z; r.w = sc.w * c.w;
        reinterpret_cast<fvec4*>(mixed)[b0 * 64 + pp] = r;
    }
}

// ---------- fallback kernels (used if ws too small / odd shapes) ----------
__global__ __launch_bounds__(256) void scores_kernel_fb(
    const float* __restrict__ x, const float* __restrict__ W,
    const float* __restrict__ bias, float* __restrict__ scores,
    int D, int M)
{
    const int b = blockIdx.x;
    __shared__ __align__(16) float x_lds[256];
    __shared__ float logits[256];
    __shared__ float wred[4];
    const int tid  = threadIdx.x;
    const int wave = tid >> 6;
    const int lane = tid & 63;
    x_lds[tid] = x[(size_t)b * D + tid];
    __syncthreads();
    const float4* W4 = reinterpret_cast<const float4*>(W);
    const float4  xv = reinterpret_cast<const float4*>(x_lds)[lane];
    for (int i = 0; i < 64; ++i) {
        const int m = wave * 64 + i;
        const float4 wv = W4[(size_t)m * 64 + lane];
        float pp = wv.x * xv.x + wv.y * xv.y + wv.z * xv.z + wv.w * xv.w;
        #pragma unroll
        for (int off = 32; off; off >>= 1) pp += __shfl_xor(pp, off, 64);
        if (lane == 0) logits[m] = pp + bias[m];
    }
    __syncthreads();
    float l = logits[tid];
    float mx = l;
    #pragma unroll
    for (int off = 32; off; off >>= 1) mx = fmaxf(mx, __shfl_xor(mx, off, 64));
    if (lane == 0) wred[wave] = mx;
    __syncthreads();
    mx = fmaxf(fmaxf(wred[0], wred[1]), fmaxf(wred[2], wred[3]));
    __syncthreads();
    const float e = expf(l - mx);
    float s = e;
    #pragma unroll
    for (int off = 32; off; off >>= 1) s += __shfl_xor(s, off, 64);
    if (lane == 0) wred[wave] = s;
    __syncthreads();
    const float tot = wred[0] + wred[1] + wred[2] + wred[3];
    scores[(size_t)b * M + tid] = e / tot;
}

__global__ __launch_bounds__(256) void neuron_kernel_fb(
    const float* __restrict__ x, const float* __restrict__ mem,
    const float* __restrict__ scores, float* __restrict__ mixed,
    float* __restrict__ mem_new, int M, int plane4)
{
    const int idx = blockIdx.x * 256 + threadIdx.x;
    if (idx >= plane4) return;
    const float4* x4   = reinterpret_cast<const float4*>(x);
    const float4* mem4 = reinterpret_cast<const float4*>(mem);
    const float4* sc4  = reinterpret_cast<const float4*>(scores);
    float4* out4       = reinterpret_cast<float4*>(mem_new);
    float4* mix4       = reinterpret_cast<float4*>(mixed);
    const float4 xv = x4[idx];
    float cx = 0.f, cy = 0.f, cz = 0.f, cw = 0.f;
    #pragma unroll 4
    for (int m = 0; m < M; ++m) {
        const float bm = (float)m;
        const size_t off = (size_t)m * plane4 + idx;
        const float4 mv = mem4[off];
        float4 nv;
        nv.x = __fsub_rn(__fadd_rn(__fmul_rn(bm, mv.x), xv.x),
                         (mv.x - THRESH > 0.f) ? THRESH : 0.f);
        nv.y = __fsub_rn(__fadd_rn(__fmul_rn(bm, mv.y), xv.y),
                         (mv.y - THRESH > 0.f) ? THRESH : 0.f);
        nv.z = __fsub_rn(__fadd_rn(__fmul_rn(bm, mv.z), xv.z),
                         (mv.z - THRESH > 0.f) ? THRESH : 0.f);
        nv.w = __fsub_rn(__fadd_rn(__fmul_rn(bm, mv.w), xv.w),
                         (mv.w - THRESH > 0.f) ? THRESH : 0.f);
        out4[off] = nv;
        cx += (nv.x - THRESH > 0.f) ? 1.f : 0.f;
        cy += (nv.y - THRESH > 0.f) ? 1.f : 0.f;
        cz += (nv.z - THRESH > 0.f) ? 1.f : 0.f;
        cw += (nv.w - THRESH > 0.f) ? 1.f : 0.f;
    }
    const float4 sc = sc4[idx];
    float4 mx;
    mx.x = sc.x * cx; mx.y = sc.y * cy; mx.z = sc.z * cz; mx.w = sc.w * cw;
    mix4[idx] = mx;
}

extern "C" void kernel_launch(void* const* d_in, const int* in_sizes, int n_in,
                              void* d_out, int out_size, void* d_ws, size_t ws_size,
                              hipStream_t stream) {
    const float* x    = (const float*)d_in[0];
    const float* mem  = (const float*)d_in[1];
    const float* W    = (const float*)d_in[2];
    const float* bias = (const float*)d_in[3];

    const int M = in_sizes[3];             // 256
    const int D = in_sizes[2] / M;         // 256
    const int B = in_sizes[0] / D;         // 1024
    const int plane  = B * D;              // 262144
    const int plane4 = plane / 4;          // 65536

    float* out_mixed  = (float*)d_out;                       // [B*D]
    float* out_mem    = out_mixed + plane;                   // [M*B*D]
    float* out_scores = out_mem + (size_t)M * plane;         // [B*M]

    const size_t wt_bytes = (size_t)M * D * sizeof(float);   // 256 KB

    const bool shapes_ok = (D == 256) && (M == 256) && (B % 2 == 0);

    if (shapes_ok && ws_size >= wt_bytes) {
        float* Wt = (float*)d_ws;
        transpose_kernel<<<(M / 32) * (D / 32), 256, 0, stream>>>(W, Wt, M, D);
        rowpair_kernel<<<B / 2, 256, 0, stream>>>(
            x, mem, Wt, bias, out_mem, out_scores, out_mixed, plane4);
    } else {
        scores_kernel_fb<<<B, 256, 0, stream>>>(x, W, bias, out_scores, D, M);
        neuron_kernel_fb<<<(plane4 + 255) / 256, 256, 0, stream>>>(
            x, mem, out_scores, out_mixed, out_mem, M, plane4);
    }
}

// Round 12
// 106.979 us; speedup vs baseline: 1.0305x; 1.0220x over previous
//
#include <hip/hip_runtime.h>

#define THRESH 1.0f

typedef float fvec4 __attribute__((ext_vector_type(4)));

__device__ __forceinline__ float rl(float v, int l) {
    return __int_as_float(__builtin_amdgcn_readlane(__float_as_int(v), l));
}

// ---------- W transpose: Wt[k][m] = W[m][k] (into d_ws) ----------
__global__ __launch_bounds__(256) void transpose_kernel(
    const float* __restrict__ W, float* __restrict__ Wt, int M, int D)
{
    __shared__ float tile[32][33];
    const int tilesK = D / 32;
    const int bx = blockIdx.x % tilesK;   // k tile
    const int by = blockIdx.x / tilesK;   // m tile
    const int lx = threadIdx.x & 31;
    const int ly = threadIdx.x >> 5;      // 0..7
    #pragma unroll
    for (int j = 0; j < 4; ++j)
        tile[ly + j * 8][lx] = W[(size_t)(by * 32 + ly + j * 8) * D + bx * 32 + lx];
    __syncthreads();
    #pragma unroll
    for (int j = 0; j < 4; ++j)
        Wt[(size_t)(bx * 32 + ly + j * 8) * M + by * 32 + lx] = tile[lx][ly + j * 8];
}

// ---------- row-pair kernel: block = rows (b0, b0+1) ----------
// Prologue (all 4 waves): thread tid owns logit m=tid for both rows.
//   Wt read ONCE per block (256 KB); x broadcast via v_readlane (no LDS pipe).
// Neuron: thread = (h=tid>>7, p=tid&127): position p of the 2-row panel,
//   m in [128h, 128h+128), counts in registers. One LDS half-combine.
// Epilogue (h==0): mixed = scores * (cnt0 + cnt1). Counts are exact ints.
// Session-best structure (R7: 106.7 us). R8-R11 variants (16 waves/CU,
// staggered prologue, prefetch-across-prologue, 2-pos/lane panel remap)
// all measured 109-121 us -> mixed R/W stream is turnaround-limited here.
__global__ __launch_bounds__(256) void rowpair_kernel(
    const float* __restrict__ x, const float* __restrict__ mem,
    const float* __restrict__ Wt, const float* __restrict__ bias,
    float* __restrict__ mem_new, float* __restrict__ scores,
    float* __restrict__ mixed, int plane4)
{
    const int b0   = blockIdx.x * 2;
    const int tid  = threadIdx.x;
    const int wave = tid >> 6;
    const int lane = tid & 63;

    __shared__ __align__(16) float sc_lds[2][256];
    __shared__ fvec4 cnt_lds[2][128];
    __shared__ float wredm[2][4];
    __shared__ float wreds[2][4];

    // ---- prologue: each wave holds both x rows in registers ----
    const fvec4 xq0 = reinterpret_cast<const fvec4*>(x)[(size_t)b0 * 64 + lane];
    const fvec4 xq1 = reinterpret_cast<const fvec4*>(x)[(size_t)(b0 + 1) * 64 + lane];

    float a0 = 0.f, a1 = 0.f;
    #pragma unroll 4
    for (int j = 0; j < 64; ++j) {
        const float w0 = Wt[(size_t)(4 * j + 0) * 256 + tid];
        const float w1 = Wt[(size_t)(4 * j + 1) * 256 + tid];
        const float w2 = Wt[(size_t)(4 * j + 2) * 256 + tid];
        const float w3 = Wt[(size_t)(4 * j + 3) * 256 + tid];
        a0 = fmaf(w0, rl(xq0.x, j), a0);
        a0 = fmaf(w1, rl(xq0.y, j), a0);
        a0 = fmaf(w2, rl(xq0.z, j), a0);
        a0 = fmaf(w3, rl(xq0.w, j), a0);
        a1 = fmaf(w0, rl(xq1.x, j), a1);
        a1 = fmaf(w1, rl(xq1.y, j), a1);
        a1 = fmaf(w2, rl(xq1.z, j), a1);
        a1 = fmaf(w3, rl(xq1.w, j), a1);
    }
    const float bv = bias[tid];
    const float l0 = a0 + bv, l1 = a1 + bv;

    float m0 = l0, m1 = l1;
    #pragma unroll
    for (int off = 32; off; off >>= 1) {
        m0 = fmaxf(m0, __shfl_xor(m0, off, 64));
        m1 = fmaxf(m1, __shfl_xor(m1, off, 64));
    }
    if (lane == 0) { wredm[0][wave] = m0; wredm[1][wave] = m1; }
    __syncthreads();
    m0 = fmaxf(fmaxf(wredm[0][0], wredm[0][1]), fmaxf(wredm[0][2], wredm[0][3]));
    m1 = fmaxf(fmaxf(wredm[1][0], wredm[1][1]), fmaxf(wredm[1][2], wredm[1][3]));

    const float e0 = expf(l0 - m0), e1 = expf(l1 - m1);
    float s0 = e0, s1 = e1;
    #pragma unroll
    for (int off = 32; off; off >>= 1) {
        s0 += __shfl_xor(s0, off, 64);
        s1 += __shfl_xor(s1, off, 64);
    }
    if (lane == 0) { wreds[0][wave] = s0; wreds[1][wave] = s1; }
    __syncthreads();
    const float t0 = wreds[0][0] + wreds[0][1] + wreds[0][2] + wreds[0][3];
    const float t1 = wreds[1][0] + wreds[1][1] + wreds[1][2] + wreds[1][3];

    const float sc0 = e0 / t0, sc1 = e1 / t1;
    sc_lds[0][tid] = sc0;
    sc_lds[1][tid] = sc1;
    scores[(size_t)b0 * 256 + tid]       = sc0;
    scores[(size_t)(b0 + 1) * 256 + tid] = sc1;

    // ---- neuron stream: full-m count in registers, half per thread ----
    const int h = tid >> 7;               // m-half
    const int p = tid & 127;              // position in 2-row panel
    const int pos4 = b0 * 64 + p;         // float4 index in [B,D] plane
    const fvec4 xv = reinterpret_cast<const fvec4*>(x)[pos4];   // L2 hit

    const fvec4* mem4 = reinterpret_cast<const fvec4*>(mem);
    fvec4* out4       = reinterpret_cast<fvec4*>(mem_new);

    float cx = 0.f, cy = 0.f, cz = 0.f, cw = 0.f;
    const int mstart = h * 128;

    #pragma unroll 8
    for (int mm = 0; mm < 128; ++mm) {
        const int m = mstart + mm;
        const float bm = (float)m;
        const size_t off = (size_t)m * plane4 + pos4;
        const fvec4 mv = __builtin_nontemporal_load(&mem4[off]);

        fvec4 nv;
        nv.x = __fsub_rn(__fadd_rn(__fmul_rn(bm, mv.x), xv.x),
                         (mv.x - THRESH > 0.f) ? THRESH : 0.f);
        nv.y = __fsub_rn(__fadd_rn(__fmul_rn(bm, mv.y), xv.y),
                         (mv.y - THRESH > 0.f) ? THRESH : 0.f);
        nv.z = __fsub_rn(__fadd_rn(__fmul_rn(bm, mv.z), xv.z),
                         (mv.z - THRESH > 0.f) ? THRESH : 0.f);
        nv.w = __fsub_rn(__fadd_rn(__fmul_rn(bm, mv.w), xv.w),
                         (mv.w - THRESH > 0.f) ? THRESH : 0.f);

        __builtin_nontemporal_store(nv, &out4[off]);

        cx += (nv.x - THRESH > 0.f) ? 1.f : 0.f;
        cy += (nv.y - THRESH > 0.f) ? 1.f : 0.f;
        cz += (nv.z - THRESH > 0.f) ? 1.f : 0.f;
        cw += (nv.w - THRESH > 0.f) ? 1.f : 0.f;
    }
    fvec4 cv; cv.x = cx; cv.y = cy; cv.z = cz; cv.w = cw;
    cnt_lds[h][p] = cv;
    __syncthreads();

    // ---- epilogue: mixed[pos] = scores_flat[pos] * total count ----
    if (h == 0) {
        const fvec4 cA = cnt_lds[0][p];
        const fvec4 cB = cnt_lds[1][p];
        const fvec4 sc = reinterpret_cast<const fvec4*>(sc_lds[p >> 6])[p & 63];
        fvec4 r;
        r.x = sc.x * (cA.x + cB.x);
        r.y = sc.y * (cA.y + cB.y);
        r.z = sc.z * (cA.z + cB.z);
        r.w = sc.w * (cA.w + cB.w);
        reinterpret_cast<fvec4*>(mixed)[pos4] = r;
    }
}

// ---------- fallback kernels (used if ws too small / odd shapes) ----------
__global__ __launch_bounds__(256) void scores_kernel_fb(
    const float* __restrict__ x, const float* __restrict__ W,
    const float* __restrict__ bias, float* __restrict__ scores,
    int D, int M)
{
    const int b = blockIdx.x;
    __shared__ __align__(16) float x_lds[256];
    __shared__ float logits[256];
    __shared__ float wred[4];
    const int tid  = threadIdx.x;
    const int wave = tid >> 6;
    const int lane = tid & 63;
    x_lds[tid] = x[(size_t)b * D + tid];
    __syncthreads();
    const float4* W4 = reinterpret_cast<const float4*>(W);
    const float4  xv = reinterpret_cast<const float4*>(x_lds)[lane];
    for (int i = 0; i < 64; ++i) {
        const int m = wave * 64 + i;
        const float4 wv = W4[(size_t)m * 64 + lane];
        float pp = wv.x * xv.x + wv.y * xv.y + wv.z * xv.z + wv.w * xv.w;
        #pragma unroll
        for (int off = 32; off; off >>= 1) pp += __shfl_xor(pp, off, 64);
        if (lane == 0) logits[m] = pp + bias[m];
    }
    __syncthreads();
    float l = logits[tid];
    float mx = l;
    #pragma unroll
    for (int off = 32; off; off >>= 1) mx = fmaxf(mx, __shfl_xor(mx, off, 64));
    if (lane == 0) wred[wave] = mx;
    __syncthreads();
    mx = fmaxf(fmaxf(wred[0], wred[1]), fmaxf(wred[2], wred[3]));
    __syncthreads();
    const float e = expf(l - mx);
    float s = e;
    #pragma unroll
    for (int off = 32; off; off >>= 1) s += __shfl_xor(s, off, 64);
    if (lane == 0) wred[wave] = s;
    __syncthreads();
    const float tot = wred[0] + wred[1] + wred[2] + wred[3];
    scores[(size_t)b * M + tid] = e / tot;
}

__global__ __launch_bounds__(256) void neuron_kernel_fb(
    const float* __restrict__ x, const float* __restrict__ mem,
    const float* __restrict__ scores, float* __restrict__ mixed,
    float* __restrict__ mem_new, int M, int plane4)
{
    const int idx = blockIdx.x * 256 + threadIdx.x;
    if (idx >= plane4) return;
    const float4* x4   = reinterpret_cast<const float4*>(x);
    const float4* mem4 = reinterpret_cast<const float4*>(mem);
    const float4* sc4  = reinterpret_cast<const float4*>(scores);
    float4* out4       = reinterpret_cast<float4*>(mem_new);
    float4* mix4       = reinterpret_cast<float4*>(mixed);
    const float4 xv = x4[idx];
    float cx = 0.f, cy = 0.f, cz = 0.f, cw = 0.f;
    #pragma unroll 4
    for (int m = 0; m < M; ++m) {
        const float bm = (float)m;
        const size_t off = (size_t)m * plane4 + idx;
        const float4 mv = mem4[off];
        float4 nv;
        nv.x = __fsub_rn(__fadd_rn(__fmul_rn(bm, mv.x), xv.x),
                         (mv.x - THRESH > 0.f) ? THRESH : 0.f);
        nv.y = __fsub_rn(__fadd_rn(__fmul_rn(bm, mv.y), xv.y),
                         (mv.y - THRESH > 0.f) ? THRESH : 0.f);
        nv.z = __fsub_rn(__fadd_rn(__fmul_rn(bm, mv.z), xv.z),
                         (mv.z - THRESH > 0.f) ? THRESH : 0.f);
        nv.w = __fsub_rn(__fadd_rn(__fmul_rn(bm, mv.w), xv.w),
                         (mv.w - THRESH > 0.f) ? THRESH : 0.f);
        out4[off] = nv;
        cx += (nv.x - THRESH > 0.f) ? 1.f : 0.f;
        cy += (nv.y - THRESH > 0.f) ? 1.f : 0.f;
        cz += (nv.z - THRESH > 0.f) ? 1.f : 0.f;
        cw += (nv.w - THRESH > 0.f) ? 1.f : 0.f;
    }
    const float4 sc = sc4[idx];
    float4 mx;
    mx.x = sc.x * cx; mx.y = sc.y * cy; mx.z = sc.z * cz; mx.w = sc.w * cw;
    mix4[idx] = mx;
}

extern "C" void kernel_launch(void* const* d_in, const int* in_sizes, int n_in,
                              void* d_out, int out_size, void* d_ws, size_t ws_size,
                              hipStream_t stream) {
    const float* x    = (const float*)d_in[0];
    const float* mem  = (const float*)d_in[1];
    const float* W    = (const float*)d_in[2];
    const float* bias = (const float*)d_in[3];

    const int M = in_sizes[3];             // 256
    const int D = in_sizes[2] / M;         // 256
    const int B = in_sizes[0] / D;         // 1024
    const int plane  = B * D;              // 262144
    const int plane4 = plane / 4;          // 65536

    float* out_mixed  = (float*)d_out;                       // [B*D]
    float* out_mem    = out_mixed + plane;                   // [M*B*D]
    float* out_scores = out_mem + (size_t)M * plane;         // [B*M]

    const size_t wt_bytes = (size_t)M * D * sizeof(float);   // 256 KB

    const bool shapes_ok = (D == 256) && (M == 256) && (B % 2 == 0);

    if (shapes_ok && ws_size >= wt_bytes) {
        float* Wt = (float*)d_ws;
        transpose_kernel<<<(M / 32) * (D / 32), 256, 0, stream>>>(W, Wt, M, D);
        rowpair_kernel<<<B / 2, 256, 0, stream>>>(
            x, mem, Wt, bias, out_mem, out_scores, out_mixed, plane4);
    } else {
        scores_kernel_fb<<<B, 256, 0, stream>>>(x, W, bias, out_scores, D, M);
        neuron_kernel_fb<<<(plane4 + 255) / 256, 256, 0, stream>>>(
            x, mem, out_scores, out_mixed, out_mem, M, plane4);
    }
}